// Round 9
// baseline (7208.410 us; speedup 1.0000x reference)
//
#include <hip/hip_runtime.h>

// ---------------------------------------------------------------------------
// VoxelSetAbstraction forward (PV-RCNN style) for MI355X
//   B=2, N_RAW=16384, N_KP=2048, M_VOX=8192, C_VOX=64
//   BEV: (2,256,200,176), stride 8, voxel 0.05, pc_min (0,-40,-3)
//   raw SA: radii (0.4,0.8) ns (16,16), MLP 4->16->16
//   conv SA: radii (1.2,2.4) ns (16,32), MLP 67->64->64
//   fusion: 416 -> 128
// ---------------------------------------------------------------------------

#define NRAW   16384
#define MVOX   8192
#define NKP    2048
#define NKPALL 4096   // B * NKP

__device__ __constant__ float kBNS = (float)0.9999950000374997; // 1/sqrt(1+1e-5)

// ---------------------------------------------------------------------------
// K0: pack points to interleaved float4 (x,y,z,intensity) + voxel centers
// ---------------------------------------------------------------------------
__global__ __launch_bounds__(256) void prep_kernel(
    const float* __restrict__ pts, const int* __restrict__ vc,
    float4* __restrict__ xyz4, float4* __restrict__ cxyz4) {
#pragma clang fp contract(off)
  int i = blockIdx.x * 256 + threadIdx.x;
  if (i < 2 * NRAW) {
    const float* p = pts + (size_t)i * 5;
    xyz4[i] = make_float4(p[1], p[2], p[3], p[4]);
  }
  if (i < 2 * MVOX) {
    const int* v = vc + (size_t)i * 4;
    cxyz4[i] = make_float4(((float)v[3] + 0.5f) * 0.2f + 0.0f,
                           ((float)v[2] + 0.5f) * 0.2f + -40.0f,
                           ((float)v[1] + 0.5f) * 0.4f + -3.0f, 0.f);
  }
}

// ---------------------------------------------------------------------------
// K0b: y-histogram sort (256 bins) per batch -> sperm (sorted-pos ->
// original local index). FPS gathers coords via sperm (warms local L2).
// Bin-internal order nondeterministic (atomic ranks) but FPS output is
// order-invariant: ties resolved by ORIGINAL index carried in registers.
// 256 consecutive sorted points ~= a 1.25m y-substrip -> tight chunk bboxes.
// ---------------------------------------------------------------------------
__global__ __launch_bounds__(1024) void sort_kernel(
    const float* __restrict__ pts, int* __restrict__ sperm) {
  const int b = blockIdx.x, t = threadIdx.x;
  __shared__ unsigned hist[256], cur[256];
  if (t < 256) hist[t] = 0u;
  __syncthreads();
  int bins[16];
#pragma unroll
  for (int k = 0; k < 16; ++k) {
    const int i = k * 1024 + t;
    const float y = pts[(size_t)(b * NRAW + i) * 5 + 2];
    int bin = (int)((y + 40.0f) * 3.2f);
    bin = bin < 0 ? 0 : (bin > 255 ? 255 : bin);
    bins[k] = bin;
    atomicAdd(&hist[bin], 1u);
  }
  __syncthreads();
  if (t == 0) {
    unsigned acc = 0;
    for (int i = 0; i < 256; ++i) { cur[i] = acc; acc += hist[i]; }
  }
  __syncthreads();
#pragma unroll
  for (int k = 0; k < 16; ++k) {
    const int i = k * 1024 + t;
    const unsigned pos = atomicAdd(&cur[bins[k]], 1u);
    sperm[b * NRAW + pos] = i;
  }
}

// ---------------------------------------------------------------------------
// Wave-wide u32 max via DPP (VALU pipe, zero DS). Lane 63 holds the result.
// ---------------------------------------------------------------------------
__device__ __forceinline__ unsigned wave_umax63(unsigned v) {
  unsigned t;
  t = (unsigned)__builtin_amdgcn_update_dpp(0, (int)v, 0xB1,  0xf, 0xf, true); v = v < t ? t : v;
  t = (unsigned)__builtin_amdgcn_update_dpp(0, (int)v, 0x4E,  0xf, 0xf, true); v = v < t ? t : v;
  t = (unsigned)__builtin_amdgcn_update_dpp(0, (int)v, 0x124, 0xf, 0xf, true); v = v < t ? t : v;
  t = (unsigned)__builtin_amdgcn_update_dpp(0, (int)v, 0x128, 0xf, 0xf, true); v = v < t ? t : v;
  t = (unsigned)__builtin_amdgcn_update_dpp(0, (int)v, 0x142, 0xa, 0xf, true); v = v < t ? t : v;
  t = (unsigned)__builtin_amdgcn_update_dpp(0, (int)v, 0x143, 0xc, 0xf, true); v = v < t ? t : v;
  return v;  // valid in lane 63
}

// ---------------------------------------------------------------------------
// K1: FPS with two-level EXACT pruning + all-LDS winner exchange.
// 16 waves x 1024 pts; chunk = 4 j's = 256 pts (~1.25m y-substrip).
// Per iteration (one barrier):
//   wave bbox test (vs cached wave max bvc) -> whole-wave skip
//   else per-chunk bbox test vs per-lane cached chunk max cmaxL[c]
//     (__any-gated); active chunks: dd=min(dd,d2) exact numpy order,
//     cmaxL refresh (3 fmax)
//   if any chunk active: bv = max(cmaxL[0..3]); DPP wave val-max; tied lanes
//     scan 16 regs for min ORIGINAL idx carrying coords; DPP idx-max;
//     winner lane's coords broadcast in-wave (ballot+shfl); cache
//     cpk = val<<32 | inv_idx<<5 | waveid<<1 | 1  and coords ccx/ccy/ccz.
//   lane63: ds atomicMax(slot[s%3], cpk) + tabC[s%3][w] = cached coords.
//   barrier; read slot -> winning waveid -> read tabC coords (NO global
//   s_load on the chain; fps stops fetching xyz4 lines per-iter).
// Pruning is conservative (x0.9999 margin vs ~1e-6 eval error): only
// provably no-op updates are skipped -> bit-identical keypoints.
// Slot/tabC triple-buffered; reset (s+2)%3 post-barrier (r7/r8-validated).
// ---------------------------------------------------------------------------
__global__ __launch_bounds__(1024, 4) void fps_kernel(
    const int* __restrict__ sperm, const float4* __restrict__ xyz4,
    float* __restrict__ kx, float* __restrict__ ky, float* __restrict__ kz) {
#pragma clang fp contract(off)
  const int b = blockIdx.x, t = threadIdx.x;
  const int w = t >> 6, lane = t & 63;
  const int wb = w * 1024, base = b * NRAW;

  __shared__ unsigned long long slot[3];
  __shared__ float4 tabC[3][16];

  int pj[16];
  float px[16], py[16], pz[16], dd[16];
#pragma unroll
  for (int j = 0; j < 16; ++j) pj[j] = sperm[base + wb + j * 64 + lane];
#pragma unroll
  for (int j = 0; j < 16; ++j) {
    const float4 q = xyz4[base + pj[j]];   // gather; warms local L2
    px[j] = q.x; py[j] = q.y; pz[j] = q.z; dd[j] = 1e10f;
  }
  if (t < 3) slot[t] = 0ULL;

  // per-chunk bboxes (exact, from actual points) + per-lane chunk max cache
  float cbnx[4], cbxx[4], cbny[4], cbxy[4], cbnz[4], cbxz[4], cmaxL[4];
#pragma unroll
  for (int c = 0; c < 4; ++c) {
    float nx = px[4 * c], xx = nx, ny = py[4 * c], xy = ny, nz = pz[4 * c], xz = nz;
#pragma unroll
    for (int j = 4 * c + 1; j < 4 * c + 4; ++j) {
      nx = fminf(nx, px[j]); xx = fmaxf(xx, px[j]);
      ny = fminf(ny, py[j]); xy = fmaxf(xy, py[j]);
      nz = fminf(nz, pz[j]); xz = fmaxf(xz, pz[j]);
    }
#pragma unroll
    for (int off = 1; off < 64; off <<= 1) {
      nx = fminf(nx, __shfl_xor(nx, off, 64)); xx = fmaxf(xx, __shfl_xor(xx, off, 64));
      ny = fminf(ny, __shfl_xor(ny, off, 64)); xy = fmaxf(xy, __shfl_xor(xy, off, 64));
      nz = fminf(nz, __shfl_xor(nz, off, 64)); xz = fmaxf(xz, __shfl_xor(xz, off, 64));
    }
    cbnx[c] = nx; cbxx[c] = xx; cbny[c] = ny; cbxy[c] = xy; cbnz[c] = nz; cbxz[c] = xz;
    cmaxL[c] = 1e10f;
  }
  // wave bbox = union of chunk bboxes
  const float wnx = fminf(fminf(cbnx[0], cbnx[1]), fminf(cbnx[2], cbnx[3]));
  const float wxx = fmaxf(fmaxf(cbxx[0], cbxx[1]), fmaxf(cbxx[2], cbxx[3]));
  const float wny = fminf(fminf(cbny[0], cbny[1]), fminf(cbny[2], cbny[3]));
  const float wxy = fmaxf(fmaxf(cbxy[0], cbxy[1]), fmaxf(cbxy[2], cbxy[3]));
  const float wnz = fminf(fminf(cbnz[0], cbnz[1]), fminf(cbnz[2], cbnz[3]));
  const float wxz = fmaxf(fmaxf(cbxz[0], cbxz[1]), fmaxf(cbxz[2], cbxz[3]));

  const float4 p0 = xyz4[base];           // first keypoint = original idx 0
  float lx = p0.x, ly = p0.y, lz = p0.z;
  if (t == 0) { kx[b * NKP] = lx; ky[b * NKP] = ly; kz[b * NKP] = lz; }

  unsigned long long cpk = ((unsigned long long)w << 1) | 1ULL;
  float ccx = lx, ccy = ly, ccz = lz;     // overwritten at s=1 (all active)
  float bvc = __builtin_inff();
  __syncthreads();

  for (int s = 1; s < NKP; ++s) {
    const int buf = s % 3;
    // wave-level prune
    float dxm = fmaxf(fmaxf(wnx - lx, lx - wxx), 0.f);
    float dym = fmaxf(fmaxf(wny - ly, ly - wxy), 0.f);
    float dzm = fmaxf(fmaxf(wnz - lz, lz - wxz), 0.f);
    const float LB2w = dxm * dxm + dym * dym + dzm * dzm;
    if (!(LB2w * 0.9999f > bvc)) {
      bool any = false;
#pragma unroll
      for (int c = 0; c < 4; ++c) {
        float cdx = fmaxf(fmaxf(cbnx[c] - lx, lx - cbxx[c]), 0.f);
        float cdy = fmaxf(fmaxf(cbny[c] - ly, ly - cbxy[c]), 0.f);
        float cdz = fmaxf(fmaxf(cbnz[c] - lz, lz - cbxz[c]), 0.f);
        const float LB2c = cdx * cdx + cdy * cdy + cdz * cdz;
        if (__any(!(LB2c * 0.9999f > cmaxL[c]))) {
          any = true;
#pragma unroll
          for (int j = 4 * c; j < 4 * c + 4; ++j) {
            float dx = px[j] - lx, dy = py[j] - ly, dz = pz[j] - lz;
            float d2 = dx * dx; d2 = d2 + dy * dy; d2 = d2 + dz * dz;
            dd[j] = fminf(dd[j], d2);
          }
          cmaxL[c] = fmaxf(fmaxf(dd[4 * c], dd[4 * c + 1]),
                           fmaxf(dd[4 * c + 2], dd[4 * c + 3]));
        }
      }
      if (any) {
        const float bv = fmaxf(fmaxf(cmaxL[0], cmaxL[1]), fmaxf(cmaxL[2], cmaxL[3]));
        const unsigned vb = __float_as_uint(bv);
        const unsigned wmax =
            (unsigned)__builtin_amdgcn_readlane((int)wave_umax63(vb), 63);
        const bool tied = (vb == wmax);
        unsigned mo = 0xFFFFFFFFu;
        float qx = 0.f, qy = 0.f, qz = 0.f;
        if (tied) {                       // >=1 lane; min ORIGINAL idx + coords
#pragma unroll
          for (int j = 0; j < 16; ++j) {
            const bool hit = (__float_as_uint(dd[j]) == wmax) && ((unsigned)pj[j] < mo);
            mo = hit ? (unsigned)pj[j] : mo;
            qx = hit ? px[j] : qx; qy = hit ? py[j] : qy; qz = hit ? pz[j] : qz;
          }
        }
        const unsigned inv = tied ? (16383u - mo) : 0u;
        const unsigned im =
            (unsigned)__builtin_amdgcn_readlane((int)wave_umax63(inv), 63);
        const unsigned mo_w = 16383u - im;
        const unsigned long long mball = __ballot(tied && mo == mo_w);
        const int l = __builtin_ctzll(mball);
        ccx = __shfl(qx, l, 64); ccy = __shfl(qy, l, 64); ccz = __shfl(qz, l, 64);
        cpk = ((unsigned long long)wmax << 32) | ((unsigned long long)im << 5) |
              ((unsigned long long)w << 1) | 1ULL;
        bvc = __uint_as_float(wmax);
      }
    }
    if (lane == 63) {
      atomicMax(&slot[buf], cpk);
      tabC[buf][w] = make_float4(ccx, ccy, ccz, 0.f);
    }
    __syncthreads();

    const unsigned long long g = slot[buf];
    const int wid = (int)((g >> 1) & 0xFULL);
    if (t == 0) slot[(s + 2) % 3] = 0ULL;   // next used at iter s+2
    const float4 cw = tabC[buf][wid];       // LDS broadcast, no global load
    lx = cw.x; ly = cw.y; lz = cw.z;
    if (t == 0) { kx[b * NKP + s] = lx; ky[b * NKP + s] = ly; kz[b * NKP + s] = lz; }
  }
}

// ---------------------------------------------------------------------------
// K2: BEV bilinear. one block per keypoint, 256 threads = 256 channels.
// ---------------------------------------------------------------------------
__global__ __launch_bounds__(256) void bev_kernel(
    const float* __restrict__ sf, const float* __restrict__ kx,
    const float* __restrict__ ky, float* __restrict__ feats) {
#pragma clang fp contract(off)
  const int kidx = blockIdx.x;
  const int c = threadIdx.x;
  const int b = kidx >> 11;
  const float x = (kx[kidx] - 0.0f) / 0.05f / 8.0f;
  const float y = (ky[kidx] - (-40.0f)) / 0.05f / 8.0f;
  const float xf = floorf(x), yf = floorf(y);
  int x0 = (int)xf;     x0 = x0 < 0 ? 0 : (x0 > 175 ? 175 : x0);
  int x1 = (int)xf + 1; x1 = x1 < 0 ? 0 : (x1 > 175 ? 175 : x1);
  int y0 = (int)yf;     y0 = y0 < 0 ? 0 : (y0 > 199 ? 199 : y0);
  int y1 = (int)yf + 1; y1 = y1 < 0 ? 0 : (y1 > 199 ? 199 : y1);
  const float x0f = (float)x0, x1f = (float)x1, y0f = (float)y0, y1f = (float)y1;
  const float wa = (x - x0f) * (y1f - y);
  const float wb = (x1f - x) * (y1f - y);
  const float wc = (x1f - x) * (y - y0f);
  const float wd = (x - x0f) * (y - y0f);
  const float* base = sf + ((size_t)b * 256 + c) * (200 * 176);
  const float fa = base[y1 * 176 + x0];
  const float fb = base[y1 * 176 + x1];
  const float fc = base[y0 * 176 + x1];
  const float fd = base[y0 * 176 + x0];
  float r = fd * wb; r = r + fc * wa; r = r + fa * wc; r = r + fb * wd;
  feats[(size_t)kidx * 416 + c] = r;
}

// ---------------------------------------------------------------------------
// K3: raw SA. one wave per (keypoint, radius). MLP 4->16->16, max-pool.
// Uses ORIGINAL-order xyz4 (ball query keeps first-16-by-original-index).
// ---------------------------------------------------------------------------
__global__ __launch_bounds__(256) void raw_sa_kernel(
    const float4* __restrict__ xyz4,
    const float* __restrict__ kx, const float* __restrict__ ky,
    const float* __restrict__ kz,
    const float* __restrict__ w0, const float* __restrict__ g0,
    const float* __restrict__ b0, const float* __restrict__ w1,
    const float* __restrict__ g1, const float* __restrict__ b1,
    float* __restrict__ feats) {
  const int wv = threadIdx.x >> 6;
  const int lane = threadIdx.x & 63;
  const int gw = blockIdx.x * 4 + wv;       // 0..8191
  const int ri = gw >> 12;                  // radius index 0/1
  const int kidx = gw & 4095;
  const int b = kidx >> 11;
  const float R2 = ri ? (float)(0.8 * 0.8) : (float)(0.4 * 0.4);

  __shared__ int   idxl[4][16];
  __shared__ float hbuf[4][16][17];

  const float kxv = kx[kidx], kyv = ky[kidx], kzv = kz[kidx];
  const int base = b * NRAW;
  int cnt = 0;
  {
#pragma clang fp contract(off)
    for (int ch = 0; ch < NRAW / 64 && cnt < 16; ++ch) {
      const float4 q = xyz4[base + ch * 64 + lane];
      float dx = kxv - q.x, dy = kyv - q.y, dz = kzv - q.z;
      float d2 = dx * dx; d2 = d2 + dy * dy; d2 = d2 + dz * dz;
      unsigned long long m = __ballot(d2 < R2);
      while (m && cnt < 16) {
        int bit = __builtin_ctzll(m);
        if (lane == 0) idxl[wv][cnt] = ch * 64 + bit;
        ++cnt;
        m &= m - 1;
      }
    }
  }
  const int outoff = kidx * 416 + 256 + ri * 16;
  if (cnt == 0) {
    if (lane < 16) feats[outoff + lane] = 0.f;
    return;
  }
  __threadfence_block();

  const int s = lane & 15, cq = lane >> 4;
  const int ss = (s < cnt) ? s : 0;          // duplicate sample 0 (matches ref pad)
  const float4 q = xyz4[base + idxl[wv][ss]];
  const float gx = q.x - kxv, gy = q.y - kyv, gz = q.z - kzv, gi = q.w;
  const int wb0 = ri * 64, cb = ri * 16;
#pragma unroll
  for (int j = 0; j < 4; ++j) {
    int c = cq * 4 + j;
    float a = gx * w0[wb0 + c];
    a = fmaf(gy, w0[wb0 + 16 + c], a);
    a = fmaf(gz, w0[wb0 + 32 + c], a);
    a = fmaf(gi, w0[wb0 + 48 + c], a);
    a = fmaf(a, g0[cb + c] * kBNS, b0[cb + c]);
    hbuf[wv][s][c] = fmaxf(a, 0.f);
  }
  __threadfence_block();
  float o0 = 0.f, o1 = 0.f, o2 = 0.f, o3 = 0.f;
  const int wb1 = ri * 256;
#pragma unroll
  for (int k = 0; k < 16; ++k) {
    float hk = hbuf[wv][s][k];
    o0 = fmaf(hk, w1[wb1 + k * 16 + cq * 4 + 0], o0);
    o1 = fmaf(hk, w1[wb1 + k * 16 + cq * 4 + 1], o1);
    o2 = fmaf(hk, w1[wb1 + k * 16 + cq * 4 + 2], o2);
    o3 = fmaf(hk, w1[wb1 + k * 16 + cq * 4 + 3], o3);
  }
  float v0 = fmaxf(fmaf(o0, g1[cb + cq * 4 + 0] * kBNS, b1[cb + cq * 4 + 0]), 0.f);
  float v1 = fmaxf(fmaf(o1, g1[cb + cq * 4 + 1] * kBNS, b1[cb + cq * 4 + 1]), 0.f);
  float v2 = fmaxf(fmaf(o2, g1[cb + cq * 4 + 2] * kBNS, b1[cb + cq * 4 + 2]), 0.f);
  float v3 = fmaxf(fmaf(o3, g1[cb + cq * 4 + 3] * kBNS, b1[cb + cq * 4 + 3]), 0.f);
#pragma unroll
  for (int off = 1; off < 16; off <<= 1) {
    v0 = fmaxf(v0, __shfl_xor(v0, off, 64));
    v1 = fmaxf(v1, __shfl_xor(v1, off, 64));
    v2 = fmaxf(v2, __shfl_xor(v2, off, 64));
    v3 = fmaxf(v3, __shfl_xor(v3, off, 64));
  }
  if (s == 0) {
    feats[outoff + cq * 4 + 0] = v0;
    feats[outoff + cq * 4 + 1] = v1;
    feats[outoff + cq * 4 + 2] = v2;
    feats[outoff + cq * 4 + 3] = v3;
  }
}

// ---------------------------------------------------------------------------
// K4: conv SA. one wave per (keypoint, radius). MLP 67->64->64, max-pool.
// ---------------------------------------------------------------------------
__global__ __launch_bounds__(256) void conv_sa_kernel(
    const float4* __restrict__ cxyz4, const float* __restrict__ vf,
    const float* __restrict__ kx, const float* __restrict__ ky,
    const float* __restrict__ kz,
    const float* __restrict__ w0, const float* __restrict__ g0,
    const float* __restrict__ b0, const float* __restrict__ w1,
    const float* __restrict__ g1, const float* __restrict__ b1,
    float* __restrict__ feats) {
  const int wv = threadIdx.x >> 6;
  const int lane = threadIdx.x & 63;
  const int gw = blockIdx.x * 4 + wv;
  const int ri = gw >> 12;
  const int kidx = gw & 4095;
  const int b = kidx >> 11;
  const int NS = ri ? 32 : 16;
  const float R2 = ri ? (float)(2.4 * 2.4) : (float)(1.2 * 1.2);

  __shared__ int   idxl[4][32];
  __shared__ float gbuf[4][64];
  __shared__ float hbuf[4][32][64];

  const float kxv = kx[kidx], kyv = ky[kidx], kzv = kz[kidx];
  const int base = b * MVOX;
  int cnt = 0;
  {
#pragma clang fp contract(off)
    for (int ch = 0; ch < MVOX / 64 && cnt < NS; ++ch) {
      const float4 q = cxyz4[base + ch * 64 + lane];
      float dx = kxv - q.x, dy = kyv - q.y, dz = kzv - q.z;
      float d2 = dx * dx; d2 = d2 + dy * dy; d2 = d2 + dz * dz;
      unsigned long long m = __ballot(d2 < R2);
      while (m && cnt < NS) {
        int bit = __builtin_ctzll(m);
        if (lane == 0) idxl[wv][cnt] = ch * 64 + bit;
        ++cnt;
        m &= m - 1;
      }
    }
  }
  const int outoff = kidx * 416 + 288 + ri * 64;
  if (cnt == 0) {
    feats[outoff + lane] = 0.f;
    return;
  }
  __threadfence_block();

  // per-lane weight columns (lane == output channel)
  const float wA0 = w0[(ri * 67 + 0) * 64 + lane];
  const float wA1 = w0[(ri * 67 + 1) * 64 + lane];
  const float wA2 = w0[(ri * 67 + 2) * 64 + lane];
  float wB[64];
#pragma unroll
  for (int k = 0; k < 64; ++k) wB[k] = w0[(ri * 67 + 3 + k) * 64 + lane];
  float wC[64];
#pragma unroll
  for (int k = 0; k < 64; ++k) wC[k] = w1[(ri * 64 + k) * 64 + lane];
  const float s0 = g0[ri * 64 + lane] * kBNS, bb0 = b0[ri * 64 + lane];
  const float s1 = g1[ri * 64 + lane] * kBNS, bb1 = b1[ri * 64 + lane];

  for (int sm = 0; sm < cnt; ++sm) {
    const int p = base + idxl[wv][sm];
    const float4 q = cxyz4[p];
    const float ox = q.x - kxv, oy = q.y - kyv, oz = q.z - kzv;
    gbuf[wv][lane] = vf[(size_t)p * 64 + lane];
    __threadfence_block();
    float acc = ox * wA0;
    acc = fmaf(oy, wA1, acc);
    acc = fmaf(oz, wA2, acc);
#pragma unroll
    for (int k4 = 0; k4 < 16; ++k4) {
      float4 g4 = *(const float4*)&gbuf[wv][k4 * 4];
      acc = fmaf(g4.x, wB[k4 * 4 + 0], acc);
      acc = fmaf(g4.y, wB[k4 * 4 + 1], acc);
      acc = fmaf(g4.z, wB[k4 * 4 + 2], acc);
      acc = fmaf(g4.w, wB[k4 * 4 + 3], acc);
    }
    hbuf[wv][sm][lane] = fmaxf(fmaf(acc, s0, bb0), 0.f);
    __threadfence_block();
  }
  float mx = -1e30f;
  for (int sm = 0; sm < cnt; ++sm) {
    float acc = 0.f;
#pragma unroll
    for (int k4 = 0; k4 < 16; ++k4) {
      float4 h4 = *(const float4*)&hbuf[wv][sm][k4 * 4];
      acc = fmaf(h4.x, wC[k4 * 4 + 0], acc);
      acc = fmaf(h4.y, wC[k4 * 4 + 1], acc);
      acc = fmaf(h4.z, wC[k4 * 4 + 2], acc);
      acc = fmaf(h4.w, wC[k4 * 4 + 3], acc);
    }
    mx = fmaxf(mx, fmaxf(fmaf(acc, s1, bb1), 0.f));
  }
  feats[outoff + lane] = mx;
}

// ---------------------------------------------------------------------------
// K5: fusion 416 -> 128 + BN + ReLU. one thread per (kp, out-channel).
// ---------------------------------------------------------------------------
__global__ __launch_bounds__(256) void fusion_kernel(
    const float* __restrict__ feats, const float* __restrict__ fw,
    const float* __restrict__ fg, const float* __restrict__ fb,
    float* __restrict__ out) {
  const int gid = blockIdx.x * 256 + threadIdx.x;
  const int kidx = gid >> 7, c = gid & 127;
  const float* f = feats + (size_t)kidx * 416;
  float acc = 0.f;
#pragma unroll 4
  for (int k = 0; k < 416; k += 4) {
    float4 fv = *(const float4*)(f + k);
    acc = fmaf(fv.x, fw[(k + 0) * 128 + c], acc);
    acc = fmaf(fv.y, fw[(k + 1) * 128 + c], acc);
    acc = fmaf(fv.z, fw[(k + 2) * 128 + c], acc);
    acc = fmaf(fv.w, fw[(k + 3) * 128 + c], acc);
  }
  out[gid] = fmaxf(fmaf(acc, fg[c] * kBNS, fb[c]), 0.f);
}

// ---------------------------------------------------------------------------
extern "C" void kernel_launch(void* const* d_in, const int* in_sizes, int n_in,
                              void* d_out, int out_size, void* d_ws, size_t ws_size,
                              hipStream_t stream) {
  (void)in_sizes; (void)n_in; (void)out_size; (void)ws_size;
  const float* pts = (const float*)d_in[0];
  const float* sf  = (const float*)d_in[1];
  const int*   vc  = (const int*)d_in[2];
  const float* vf  = (const float*)d_in[3];
  const float* raw_w0 = (const float*)d_in[4];
  const float* raw_g0 = (const float*)d_in[5];
  const float* raw_b0 = (const float*)d_in[6];
  const float* raw_w1 = (const float*)d_in[7];
  const float* raw_g1 = (const float*)d_in[8];
  const float* raw_b1 = (const float*)d_in[9];
  const float* conv_w0 = (const float*)d_in[10];
  const float* conv_g0 = (const float*)d_in[11];
  const float* conv_b0 = (const float*)d_in[12];
  const float* conv_w1 = (const float*)d_in[13];
  const float* conv_g1 = (const float*)d_in[14];
  const float* conv_b1 = (const float*)d_in[15];
  const float* fus_w = (const float*)d_in[16];
  const float* fus_g = (const float*)d_in[17];
  const float* fus_b = (const float*)d_in[18];
  float* out = (float*)d_out;

  float* W = (float*)d_ws;
  float4* xyz4  = (float4*)W;             // 32768 float4 = 131072 floats
  float4* cxyz4 = (float4*)(W + 131072);  // 16384 float4 = 65536 floats
  float* kx    = W + 196608;              // 4096 each
  float* ky    = W + 200704;
  float* kz    = W + 204800;
  float* feats = W + 208896;              // 4096 * 416
  // fps-only scratch ALIASED into the feats region (fps completes before any
  // feats writes): sorted-pos -> original index permutation
  int* sperm = (int*)(W + 208896);        // 32768 ints

  prep_kernel<<<128, 256, 0, stream>>>(pts, vc, xyz4, cxyz4);
  sort_kernel<<<2, 1024, 0, stream>>>(pts, sperm);
  fps_kernel<<<2, 1024, 0, stream>>>(sperm, xyz4, kx, ky, kz);
  bev_kernel<<<NKPALL, 256, 0, stream>>>(sf, kx, ky, feats);
  raw_sa_kernel<<<2048, 256, 0, stream>>>(xyz4, kx, ky, kz,
                                          raw_w0, raw_g0, raw_b0, raw_w1, raw_g1, raw_b1,
                                          feats);
  conv_sa_kernel<<<2048, 256, 0, stream>>>(cxyz4, vf, kx, ky, kz,
                                           conv_w0, conv_g0, conv_b0, conv_w1, conv_g1, conv_b1,
                                           feats);
  fusion_kernel<<<2048, 256, 0, stream>>>(feats, fus_w, fus_g, fus_b, out);
}